// Round 1
// baseline (367.922 us; speedup 1.0000x reference)
//
#include <hip/hip_runtime.h>
#include <math.h>

// PillarHist: per-row histogram (64 bins x {count, mean_z, mean_r}) -> Linear(192->64) -> BatchNorm(train) -> ReLU
// K1: hist + GEMM + BN partial sums.  K2: reduce partials -> scale/shift.  K3: apply BN+ReLU in-place on d_out.

#define NBLK1 1024
#define ZMINF (-3.0f)
#define INV_BIN 16.0f   // 1 / BIN_SIZE, BIN_SIZE = 4/64 = 0.0625 (exact pow2 -> div == mul by 16)

__device__ __forceinline__ float readlane_f(float v, int l) {
    return __int_as_float(__builtin_amdgcn_readlane(__float_as_int(v), l));
}

__global__ __launch_bounds__(256, 3)
void k1_hist_linear(const float4* __restrict__ feat,     // [M*64] float4 (C=4)
                    const int*    __restrict__ nump,     // [M]
                    const float*  __restrict__ W,        // [64,192] row-major
                    const float*  __restrict__ bvec,     // [64]
                    float*        __restrict__ xout,     // [M,64] (d_out, pre-BN)
                    float*        __restrict__ partials, // [NBLK1,128]
                    int M, int iters)
{
    __shared__ float sWt[192 * 65];  // W transposed [j][f], padded stride 65 (conflict-free stage + read)
    __shared__ float sH[4 * 192];    // per-wave hist build area; reused for final reduction (needs 512)

    const int tid = threadIdx.x;
    // Stage W transposed: Wt[j*65+f] = W[f*192+j]. Coalesced read, conflict-free LDS write.
    for (int e = tid; e < 64 * 192; e += 256) {
        int f = e / 192;
        int j = e - f * 192;
        sWt[j * 65 + f] = W[e];
    }

    const int wave = tid >> 6;
    const int lane = tid & 63;
    float* hc = &sH[wave * 192];
    float* hz = hc + 64;
    float* hr = hc + 128;

    const float bv = bvec[lane];
    const int gwave = blockIdx.x * 4 + wave;
    const int totalWaves = NBLK1 * 4;
    float psum = 0.f, psq = 0.f;
    __syncthreads();

    for (int it = 0; it < iters; ++it) {
        const int rowbase = (it * totalWaves + gwave) * 4;
        float cv[4], mzv[4], mrv[4];

        // ---- build 4 rows' histograms; means land in registers (lane == bin) ----
        #pragma unroll
        for (int r = 0; r < 4; ++r) {
            const int row = rowbase + r;
            const bool active = row < M;
            hc[lane] = 0.f; hz[lane] = 0.f; hr[lane] = 0.f;
            __syncthreads();
            if (active) {
                const int np = nump[row];
                float4 v = feat[row * 64 + lane];
                if (lane < np) {
                    const float z = v.z, rr = v.w;
                    int bi = (int)((z - ZMINF) * INV_BIN);  // trunc toward 0, matches astype(int32)
                    bi = min(max(bi, 0), 63);
                    atomicAdd(&hc[bi], 1.0f);
                    atomicAdd(&hz[bi], z);
                    atomicAdd(&hr[bi], rr);
                }
            }
            __syncthreads();
            const float c = hc[lane];
            const float d = c + 1e-5f;
            cv[r]  = c;
            mzv[r] = hz[lane] / d;
            mrv[r] = hr[lane] / d;
            // per-lane read-then-zero next iter is race-free (lane-private addrs); barrier after zero orders scatter
        }

        // ---- GEMM: lane = channel f; x[f] = b[f] + sum_j c*W[f,3j] + mz*W[f,3j+1] + mr*W[f,3j+2] ----
        float acc[4];
        #pragma unroll
        for (int r = 0; r < 4; ++r) acc[r] = bv;

        #pragma unroll 4
        for (int j = 0; j < 64; ++j) {
            const float w0 = sWt[(3 * j + 0) * 65 + lane];
            const float w1 = sWt[(3 * j + 1) * 65 + lane];
            const float w2 = sWt[(3 * j + 2) * 65 + lane];
            #pragma unroll
            for (int r = 0; r < 4; ++r) {
                acc[r] += readlane_f(cv[r], j)  * w0;
                acc[r] += readlane_f(mzv[r], j) * w1;
                acc[r] += readlane_f(mrv[r], j) * w2;
            }
        }

        #pragma unroll
        for (int r = 0; r < 4; ++r) {
            const int row = rowbase + r;
            if (row < M) {
                xout[row * 64 + lane] = acc[r];
                psum += acc[r];
                psq  += acc[r] * acc[r];
            }
        }
    }

    // ---- block-level BN partial reduction ----
    __syncthreads();
    sH[wave * 128 + lane]      = psum;
    sH[wave * 128 + 64 + lane] = psq;
    __syncthreads();
    if (wave == 0) {
        float s = sH[lane] + sH[128 + lane] + sH[256 + lane] + sH[384 + lane];
        float q = sH[64 + lane] + sH[192 + lane] + sH[320 + lane] + sH[448 + lane];
        partials[blockIdx.x * 128 + lane]      = s;
        partials[blockIdx.x * 128 + 64 + lane] = q;
    }
}

__global__ __launch_bounds__(1024)
void k2_bnstats(const float* __restrict__ partials,
                const float* __restrict__ gamma,
                const float* __restrict__ beta,
                float* __restrict__ scsh,
                float invM)
{
    __shared__ float sred[1024];
    const int t = threadIdx.x;
    const int k = t & 127;
    const int half = t >> 7;   // 0..7
    float s = 0.f;
    for (int b = half; b < NBLK1; b += 8) s += partials[b * 128 + k];
    sred[half * 128 + k] = s;
    __syncthreads();
    if (t < 128) {
        float tot = 0.f;
        #pragma unroll
        for (int h = 0; h < 8; ++h) tot += sred[h * 128 + t];
        sred[t] = tot;
    }
    __syncthreads();
    if (t < 64) {
        const float mu  = sred[t] * invM;
        const float q   = sred[64 + t] * invM;
        const float var = q - mu * mu;
        const float rstd = 1.0f / sqrtf(var + 1e-5f);
        const float a = gamma[t] * rstd;
        const float c = beta[t] - mu * a;
        scsh[t] = a;
        scsh[64 + t] = c;
    }
}

__global__ __launch_bounds__(256)
void k3_bn_apply(float4* __restrict__ x, const float* __restrict__ scsh, int n4)
{
    const int i = blockIdx.x * 256 + threadIdx.x;
    if (i >= n4) return;
    const float4* a4 = (const float4*)scsh;
    const float4 a = a4[i & 15];        // 64 channels / 4 per float4 -> 16 vectors
    const float4 c = a4[16 + (i & 15)];
    float4 v = x[i];
    v.x = fmaxf(fmaf(v.x, a.x, c.x), 0.f);
    v.y = fmaxf(fmaf(v.y, a.y, c.y), 0.f);
    v.z = fmaxf(fmaf(v.z, a.z, c.z), 0.f);
    v.w = fmaxf(fmaf(v.w, a.w, c.w), 0.f);
    x[i] = v;
}

extern "C" void kernel_launch(void* const* d_in, const int* in_sizes, int n_in,
                              void* d_out, int out_size, void* d_ws, size_t ws_size,
                              hipStream_t stream) {
    const float4* feat  = (const float4*)d_in[0];  // [M,64,4] fp32
    const int*    nump  = (const int*)d_in[1];     // [M]
    // d_in[2] = coors (unused by reference output)
    const float*  W     = (const float*)d_in[3];   // [64,192]
    const float*  bvec  = (const float*)d_in[4];   // [64]
    const float*  gamma = (const float*)d_in[5];   // [64]
    const float*  beta  = (const float*)d_in[6];   // [64]

    const int M = in_sizes[1];
    float* xout     = (float*)d_out;               // pre-BN x lives in d_out
    float* partials = (float*)d_ws;                // [NBLK1,128]
    float* scsh     = partials + NBLK1 * 128;      // [128] scale/shift

    const int totalWaves = NBLK1 * 4;
    const int groups = (M + 3) / 4;
    const int iters = (groups + totalWaves - 1) / totalWaves;

    k1_hist_linear<<<NBLK1, 256, 0, stream>>>(feat, nump, W, bvec, xout, partials, M, iters);
    k2_bnstats<<<1, 1024, 0, stream>>>(partials, gamma, beta, scsh, 1.0f / (float)M);

    const int n4 = out_size / 4;
    k3_bn_apply<<<(n4 + 255) / 256, 256, 0, stream>>>((float4*)d_out, scsh, n4);
}